// Round 7
// baseline (208.830 us; speedup 1.0000x reference)
//
#include <hip/hip_runtime.h>
#include <stdint.h>

#define B_ 4
#define N_ 4096
#define C_ 256
#define LOG2E 1.44269504088896340736f
#define SOFT_OFF 88.0f

typedef float f32x4 __attribute__((ext_vector_type(4)));
typedef float f32x16 __attribute__((ext_vector_type(16)));
typedef short s16x8 __attribute__((ext_vector_type(8)));
typedef __bf16 bf16x8 __attribute__((ext_vector_type(8)));
typedef _Float16 f16x8 __attribute__((ext_vector_type(8)));

static __device__ __forceinline__ unsigned short f2bf(float f) {
    union { float f; uint32_t u; } v; v.f = f;
    return (unsigned short)((v.u + 0x7FFFu + ((v.u >> 16) & 1u)) >> 16);
}
static __device__ __forceinline__ unsigned short f2bf_rh(float f) {
    union { float f; uint32_t u; } v; v.f = f;
    return (unsigned short)((v.u + 0x8000u) >> 16);
}

// ---------- wprep: coalesced LDS transpose, W -> WT f16 [320][256] ----------
__global__ __launch_bounds__(256) void wprep(
    const float* __restrict__ Wf, const float* __restrict__ Wg,
    const float* __restrict__ Wh, _Float16* __restrict__ WT)
{
    __shared__ float tile[64][33];
    const int t = blockIdx.x, kc = blockIdx.y, tid = threadIdx.x;
    const float* src; int stride;
    if (t == 0)      { src = Wf;                stride = 32;  }
    else if (t == 1) { src = Wg;                stride = 32;  }
    else             { src = Wh + (t - 2) * 32; stride = 256; }

    const int c = tid & 31, a = tid >> 5;
    #pragma unroll
    for (int p = 0; p < 8; p++) {
        int kk = p * 8 + a;
        tile[kk][c] = src[(size_t)(kc * 64 + kk) * stride + c];
    }
    __syncthreads();
    const int kk = tid & 63, aa = tid >> 6;
    #pragma unroll
    for (int p = 0; p < 8; p++) {
        int cc = p * 4 + aa;
        WT[(size_t)(t * 32 + cc) * 256 + kc * 64 + kk] = (_Float16)tile[kk][cc];
    }
}

// ---------- proj v6: 1 tile/wave, batched reg-prefetch, no loop barriers -----
__global__ __launch_bounds__(256, 3) void proj_kernel(
    const float* __restrict__ x,
    const float* __restrict__ bfp, const float* __restrict__ bgp,
    const float* __restrict__ bhp,
    const _Float16* __restrict__ WT,
    _Float16* __restrict__ qf16, _Float16* __restrict__ kf16,
    unsigned short* __restrict__ v_frag)
{
    __shared__ __align__(16) _Float16 xs[64 * 256];            // 32 KB, swizzled
    __shared__ __align__(16) unsigned short tbuf[4][32 * 40];  // 10 KB

    const int tid  = threadIdx.x;
    const int lane = tid & 63;
    const int wave = tid >> 6;
    const int m_   = lane & 31;
    const int k8   = lane >> 5;
    const int row0 = blockIdx.x * 64;
    const int b    = row0 >> 12;
    const int n0   = row0 & 4095;
    const int kt   = n0 >> 6;

    #pragma unroll
    for (int i = 0; i < 8; i++) {
        int r  = 8 * i + (tid >> 5);
        int c5 = tid & 31;
        const f32x4* src = (const f32x4*)(x + (size_t)(row0 + r) * 256 + c5 * 8);
        f32x4 a = src[0], c4 = src[1];
        f16x8 h = { (_Float16)a.x, (_Float16)a.y, (_Float16)a.z, (_Float16)a.w,
                    (_Float16)c4.x, (_Float16)c4.y, (_Float16)c4.z, (_Float16)c4.w };
        int chunk = (((r >> 5) * 32 + c5)) * 32 + ((r & 31) ^ (c5 & 7));
        *(f16x8*)(xs + chunk * 8) = h;
    }
    __syncthreads();

    const int rowsub = wave & 1;
    const int tile   = blockIdx.y * 2 + (wave >> 1);
    const _Float16* wb = WT + (size_t)(tile * 32 + m_) * 256 + k8 * 8;

    f32x16 acc;
    #pragma unroll
    for (int i = 0; i < 16; i++) acc[i] = 0.f;

    f16x8 Bb[2][4];
    #pragma unroll
    for (int j = 0; j < 4; j++) Bb[0][j] = *(const f16x8*)(wb + j * 16);
    #pragma unroll
    for (int g4 = 0; g4 < 4; g4++) {
        const int cur = g4 & 1, nxt = cur ^ 1;
        if (g4 < 3)
            #pragma unroll
            for (int j = 0; j < 4; j++)
                Bb[nxt][j] = *(const f16x8*)(wb + (g4 * 4 + 4 + j) * 16);
        #pragma unroll
        for (int j = 0; j < 4; j++) {
            int ks = g4 * 4 + j;
            f16x8 A = *(const f16x8*)(xs + ((rowsub * 32 + ks * 2 + k8) * 32
                                            + (m_ ^ ((ks * 2 + k8) & 7))) * 8);
            acc = __builtin_amdgcn_mfma_f32_32x32x16_f16(A, Bb[cur][j], acc, 0, 0, 0);
        }
    }

    if (tile < 2) {            // f -> kf16, g -> qf16
        float bias = (tile == 0) ? bfp[m_] : bgp[m_];
        _Float16* dst = (tile == 0) ? kf16 : qf16;
        #pragma unroll
        for (int r = 0; r < 16; r++) {
            int m = (r & 3) + 8 * (r >> 2) + 4 * k8;
            int row = row0 + rowsub * 32 + m;
            dst[(size_t)row * 32 + m_] = (_Float16)(acc[r] + bias);
        }
    } else {                   // h -> v_frag[b][chg][kt][oct][chsl][ch32][key8]
        const int ht   = tile - 2;
        const int chgv = ht >> 2, chslv = ht & 3;
        float bias = bhp[ht * 32 + m_];
        unsigned short* buf = tbuf[wave];
        #pragma unroll
        for (int u = 0; u < 8; u++) {
            int r = 2 * u;
            int m = (r & 3) + 8 * (r >> 2) + 4 * k8;
            uint32_t v = (uint32_t)f2bf(acc[r] + bias)
                       | ((uint32_t)f2bf(acc[r + 1] + bias) << 16);
            *(uint32_t*)(buf + m_ * 40 + m) = v;
        }
        #pragma unroll
        for (int u = 0; u < 2; u++) {
            int idx2 = u * 64 + lane;
            int chr = idx2 >> 2, q8 = idx2 & 3;
            s16x8 vv = *(const s16x8*)(buf + chr * 40 + q8 * 8);
            int oct = rowsub * 4 + q8;
            size_t e = (((((size_t)(b * 2 + chgv) * 64 + kt) * 8 + oct) * 4
                          + chslv) * 32 + chr) * 8;
            *(s16x8*)(v_frag + e) = vv;
        }
    }
}

// ---------- flash attention v7: raw-barrier pipeline, 1 barrier/iter ---------
// grid (64 qt, 2 chg, 4 b), 512 thr = 8 waves.
// S (waves 0-3): qsub=w&1, ksub=w>>1 -> S(32q x 32k) -> P_s[qsub][kt&1].
// PV (all 8): qsub=w&1, chsl=w>>1, Bv prefetched 1 iter ahead into regs.
// Barrier = "s_waitcnt lgkmcnt(0); s_barrier" (no vmcnt drain -> prefetches
// stay in flight across the barrier; safe because nothing crossing the
// barrier is a global->LDS op — P is LDS-only, Bv/K are register loads).
#define ATTN_STEP(KT, PAR, BCUR, BNXT, KC0, KC1, KN0, KN1)                       \
    {                                                                            \
        const int ktn_ = ((KT) < 63) ? (KT) + 1 : 63;                            \
        _Pragma("unroll")                                                        \
        for (int ks_ = 0; ks_ < 4; ks_++)                                        \
            BNXT[ks_] = *(const bf16x8*)(vb + (size_t)ktn_ * 8192 + ks_ * 2048); \
        if (is_s) {                                                              \
            const _Float16* kp_ = kf16 + (bn + ktn_ * 64 + ksub * 32 + m_) * 32; \
            KN0 = *(const f16x8*)(kp_ + k8 * 8);                                 \
            KN1 = *(const f16x8*)(kp_ + 16 + k8 * 8);                            \
            f32x16 s_;                                                           \
            _Pragma("unroll")                                                    \
            for (int i = 0; i < 16; i++) s_[i] = 0.f;                            \
            s_ = __builtin_amdgcn_mfma_f32_32x32x16_f16(Aq0, KC0, s_, 0, 0, 0);  \
            s_ = __builtin_amdgcn_mfma_f32_32x32x16_f16(Aq1, KC1, s_, 0, 0, 0);  \
            unsigned short* Pb_ = P_s[qsub][PAR];                                \
            _Pragma("unroll")                                                    \
            for (int r = 0; r < 16; r++) {                                       \
                float p_ = __builtin_amdgcn_exp2f(fmaf(s_[r], LOG2E, -SOFT_OFF));\
                l_acc[r] += p_;                                                  \
                int mi_ = (r & 3) + 8 * (r >> 2) + 4 * k8;                       \
                Pb_[(octet * 32 + (mi_ ^ octsw)) * 8 + kofs] = f2bf_rh(p_);      \
            }                                                                    \
        }                                                                        \
        __asm volatile("s_waitcnt lgkmcnt(0)\n\ts_barrier" ::: "memory");        \
        const unsigned short* Pr_ = P_s[qsub][PAR];                              \
        _Pragma("unroll")                                                        \
        for (int ks_ = 0; ks_ < 4; ks_++) {                                      \
            int oct_ = ks_ * 2 + k8;                                             \
            bf16x8 Ap_ = *(const bf16x8*)(Pr_ + (oct_ * 32 + (m_ ^ (oct_ & 3))) * 8); \
            acc = __builtin_amdgcn_mfma_f32_32x32x16_bf16(Ap_, BCUR[ks_], acc, 0, 0, 0); \
        }                                                                        \
    }

__global__ __launch_bounds__(512, 4) void attn_kernel(
    const _Float16* __restrict__ qf16, const _Float16* __restrict__ kf16,
    const unsigned short* __restrict__ v_frag,
    const float* __restrict__ x, const float* __restrict__ gamma_p,
    float* __restrict__ out)
{
    __shared__ __align__(16) unsigned short P_s[2][2][2048]; // [qsub][parity]
    __shared__ float l_s[2][2][32];                          // [qsub][ksub][q]

    const int tid  = threadIdx.x;
    const int lane = tid & 63;
    const int wave = tid >> 6;
    const int qsub = wave & 1;
    const int chsl = wave >> 1;
    const int m_   = lane & 31;
    const int k8   = lane >> 5;
    const int qt   = blockIdx.x;
    const int chg  = blockIdx.y;
    const int b    = blockIdx.z;
    const size_t bn = (size_t)b * N_;
    const int ch0  = chg * 128;
    const bool is_s = (wave < 4);
    const int ksub  = wave >> 1;
    const int octet = ksub * 4 + (m_ >> 3);
    const int octsw = octet & 3;
    const int kofs  = m_ & 7;

    const unsigned short* vb = v_frag + (size_t)(b * 2 + chg) * 524288
                             + (size_t)k8 * 1024 + chsl * 256 + m_ * 8;

    f16x8 Aq0 = {}, Aq1 = {}, Kca0 = {}, Kca1 = {}, Kcb0 = {}, Kcb1 = {};
    if (is_s) {
        const int qrow = qt * 64 + qsub * 32 + m_;
        Aq0 = *(const f16x8*)(qf16 + (bn + qrow) * 32 + k8 * 8);
        Aq1 = *(const f16x8*)(qf16 + (bn + qrow) * 32 + 16 + k8 * 8);
        const _Float16* kp = kf16 + (bn + ksub * 32 + m_) * 32;
        Kca0 = *(const f16x8*)(kp + k8 * 8);
        Kca1 = *(const f16x8*)(kp + 16 + k8 * 8);
    }
    bf16x8 Ba[4], Bb2[4];
    #pragma unroll
    for (int ks = 0; ks < 4; ks++)
        Ba[ks] = *(const bf16x8*)(vb + ks * 2048);

    f32x16 acc;
    float l_acc[16];
    #pragma unroll
    for (int i = 0; i < 16; i++) { acc[i] = 0.f; l_acc[i] = 0.f; }

    for (int kt = 0; kt < 64; kt += 2) {
        ATTN_STEP(kt,     0, Ba,  Bb2, Kca0, Kca1, Kcb0, Kcb1);
        ATTN_STEP(kt + 1, 1, Bb2, Ba,  Kcb0, Kcb1, Kca0, Kca1);
    }

    if (is_s) {
        #pragma unroll
        for (int off = 1; off < 32; off <<= 1)
            #pragma unroll
            for (int r = 0; r < 16; r++)
                l_acc[r] += __shfl_xor(l_acc[r], off, 64);
        if (m_ == 0) {
            #pragma unroll
            for (int r = 0; r < 16; r++) {
                int q = (r & 3) + 8 * (r >> 2) + 4 * k8;
                l_s[qsub][ksub][q] = l_acc[r];
            }
        }
    }
    __syncthreads();

    const float gamma = *gamma_p;
    #pragma unroll
    for (int r = 0; r < 16; r++) {
        int q = (r & 3) + 8 * (r >> 2) + 4 * k8;
        float l = l_s[qsub][0][q] + l_s[qsub][1][q];
        size_t idx = (bn + qt * 64 + qsub * 32 + q) * 256 + ch0 + chsl * 32 + m_;
        out[idx] = gamma * (acc[r] / l) + x[idx];
    }
}

extern "C" void kernel_launch(void* const* d_in, const int* in_sizes, int n_in,
                              void* d_out, int out_size, void* d_ws, size_t ws_size,
                              hipStream_t stream) {
    const float* x   = (const float*)d_in[0];
    const float* Wf  = (const float*)d_in[1];
    const float* bfp = (const float*)d_in[2];
    const float* Wg  = (const float*)d_in[3];
    const float* bgp = (const float*)d_in[4];
    const float* Wh  = (const float*)d_in[5];
    const float* bhp = (const float*)d_in[6];
    const float* gam = (const float*)d_in[7];
    float* out = (float*)d_out;

    unsigned char* ws = (unsigned char*)d_ws;
    const size_t MB = 1 << 20;
    _Float16* WT    = (_Float16*)(ws);              // [320][256] f16, 160 KB
    _Float16* qf16  = (_Float16*)(ws + 1 * MB);     // [B*N][32] f16 (queries g)
    _Float16* kf16  = (_Float16*)(ws + 2 * MB);     // [B*N][32] f16 (keys f)
    unsigned short* v_frag = (unsigned short*)(ws + 3 * MB);  // 8.4 MB B-frag layout

    wprep<<<dim3(10, 4), dim3(256), 0, stream>>>(Wf, Wg, Wh, WT);
    proj_kernel<<<dim3(256, 5), dim3(256), 0, stream>>>(
        x, bfp, bgp, bhp, WT, qf16, kf16, v_frag);
    attn_kernel<<<dim3(64, 2, 4), dim3(512), 0, stream>>>(
        qf16, kf16, v_frag, x, gam, out);
}

// Round 8
// 172.588 us; speedup vs baseline: 1.2100x; 1.2100x over previous
//
#include <hip/hip_runtime.h>
#include <stdint.h>

#define B_ 4
#define N_ 4096
#define C_ 256
#define LOG2E 1.44269504088896340736f
#define SOFT_OFF 88.0f

typedef float f32x4 __attribute__((ext_vector_type(4)));
typedef float f32x16 __attribute__((ext_vector_type(16)));
typedef short s16x8 __attribute__((ext_vector_type(8)));
typedef __bf16 bf16x8 __attribute__((ext_vector_type(8)));
typedef _Float16 f16x8 __attribute__((ext_vector_type(8)));

static __device__ __forceinline__ unsigned short f2bf(float f) {
    union { float f; uint32_t u; } v; v.f = f;
    return (unsigned short)((v.u + 0x7FFFu + ((v.u >> 16) & 1u)) >> 16);
}
static __device__ __forceinline__ unsigned short f2bf_rh(float f) {
    union { float f; uint32_t u; } v; v.f = f;
    return (unsigned short)((v.u + 0x8000u) >> 16);
}

// ---------- wprep: coalesced LDS transpose, W -> WT f16 [320][256] ----------
__global__ __launch_bounds__(256) void wprep(
    const float* __restrict__ Wf, const float* __restrict__ Wg,
    const float* __restrict__ Wh, _Float16* __restrict__ WT)
{
    __shared__ float tile[64][33];
    const int t = blockIdx.x, kc = blockIdx.y, tid = threadIdx.x;
    const float* src; int stride;
    if (t == 0)      { src = Wf;                stride = 32;  }
    else if (t == 1) { src = Wg;                stride = 32;  }
    else             { src = Wh + (t - 2) * 32; stride = 256; }

    const int c = tid & 31, a = tid >> 5;
    #pragma unroll
    for (int p = 0; p < 8; p++) {
        int kk = p * 8 + a;
        tile[kk][c] = src[(size_t)(kc * 64 + kk) * stride + c];
    }
    __syncthreads();
    const int kk = tid & 63, aa = tid >> 6;
    #pragma unroll
    for (int p = 0; p < 8; p++) {
        int cc = p * 4 + aa;
        WT[(size_t)(t * 32 + cc) * 256 + kc * 64 + kk] = (_Float16)tile[kk][cc];
    }
}

// ---------- proj v7: 3 tiles/wave, x read 2x, batched reg-prefetch -----------
// grid (256, 2): y=0 -> tiles 0-5 (f,g,h0-h3), y=1 -> tiles 6-9 (h4-h7).
// 4 waves: rowsub = wave&1 (32 rows), tg = wave>>1 -> 3 (half0) / 2 (half1) tiles.
__global__ __launch_bounds__(256, 2) void proj_kernel(
    const float* __restrict__ x,
    const float* __restrict__ bfp, const float* __restrict__ bgp,
    const float* __restrict__ bhp,
    const _Float16* __restrict__ WT,
    _Float16* __restrict__ qf16, _Float16* __restrict__ kf16,
    unsigned short* __restrict__ v_frag)
{
    __shared__ __align__(16) _Float16 xs[64 * 256];            // 32 KB, swizzled
    __shared__ __align__(16) unsigned short tbuf[4][32 * 40];  // 10 KB

    const int tid  = threadIdx.x;
    const int lane = tid & 63;
    const int wave = tid >> 6;
    const int m_   = lane & 31;
    const int k8   = lane >> 5;
    const int row0 = blockIdx.x * 64;
    const int half = blockIdx.y;
    const int b    = row0 >> 12;
    const int n0   = row0 & 4095;
    const int kt   = n0 >> 6;

    #pragma unroll
    for (int i = 0; i < 8; i++) {
        int r  = 8 * i + (tid >> 5);
        int c5 = tid & 31;
        const f32x4* src = (const f32x4*)(x + (size_t)(row0 + r) * 256 + c5 * 8);
        f32x4 a = src[0], c4 = src[1];
        f16x8 h = { (_Float16)a.x, (_Float16)a.y, (_Float16)a.z, (_Float16)a.w,
                    (_Float16)c4.x, (_Float16)c4.y, (_Float16)c4.z, (_Float16)c4.w };
        int chunk = (((r >> 5) * 32 + c5)) * 32 + ((r & 31) ^ (c5 & 7));
        *(f16x8*)(xs + chunk * 8) = h;
    }
    __syncthreads();

    const int rowsub = wave & 1;
    const int tg     = wave >> 1;
    const int ntile  = (half == 0) ? 3 : 2;
    const int t_base = (half == 0) ? tg * 3 : 6 + tg * 2;
    const _Float16* wb[3];
    #pragma unroll
    for (int t = 0; t < 3; t++)
        wb[t] = WT + (size_t)((t_base + (t < ntile ? t : 0)) * 32 + m_) * 256 + k8 * 8;

    f32x16 acc[3];
    #pragma unroll
    for (int t = 0; t < 3; t++)
        #pragma unroll
        for (int i = 0; i < 16; i++) acc[t][i] = 0.f;

    f16x8 Bb[2][4][3];
    #pragma unroll
    for (int j = 0; j < 4; j++)
        #pragma unroll
        for (int t = 0; t < 3; t++) {
            if (t >= ntile) break;
            Bb[0][j][t] = *(const f16x8*)(wb[t] + j * 16);
        }
    #pragma unroll
    for (int g4 = 0; g4 < 4; g4++) {
        const int cur = g4 & 1, nxt = cur ^ 1;
        if (g4 < 3)
            #pragma unroll
            for (int j = 0; j < 4; j++)
                #pragma unroll
                for (int t = 0; t < 3; t++) {
                    if (t >= ntile) break;
                    Bb[nxt][j][t] = *(const f16x8*)(wb[t] + (g4 * 4 + 4 + j) * 16);
                }
        #pragma unroll
        for (int j = 0; j < 4; j++) {
            int ks = g4 * 4 + j;
            f16x8 A = *(const f16x8*)(xs + ((rowsub * 32 + ks * 2 + k8) * 32
                                            + (m_ ^ ((ks * 2 + k8) & 7))) * 8);
            #pragma unroll
            for (int t = 0; t < 3; t++) {
                if (t >= ntile) break;
                acc[t] = __builtin_amdgcn_mfma_f32_32x32x16_f16(A, Bb[cur][j][t],
                                                                acc[t], 0, 0, 0);
            }
        }
    }

    #pragma unroll
    for (int t = 0; t < 3; t++) {
        if (t >= ntile) break;
        const int tile = t_base + t;
        if (tile < 2) {            // f -> kf16, g -> qf16
            float bias = (tile == 0) ? bfp[m_] : bgp[m_];
            _Float16* dst = (tile == 0) ? kf16 : qf16;
            #pragma unroll
            for (int r = 0; r < 16; r++) {
                int m = (r & 3) + 8 * (r >> 2) + 4 * k8;
                int row = row0 + rowsub * 32 + m;
                dst[(size_t)row * 32 + m_] = (_Float16)(acc[t][r] + bias);
            }
        } else {                   // h -> v_frag[b][chg][kt][oct][chsl][ch32][key8]
            const int ht   = tile - 2;
            const int chgv = ht >> 2, chslv = ht & 3;
            float bias = bhp[ht * 32 + m_];
            unsigned short* buf = tbuf[wave];
            #pragma unroll
            for (int u = 0; u < 8; u++) {
                int r = 2 * u;
                int m = (r & 3) + 8 * (r >> 2) + 4 * k8;
                uint32_t v = (uint32_t)f2bf(acc[t][r] + bias)
                           | ((uint32_t)f2bf(acc[t][r + 1] + bias) << 16);
                *(uint32_t*)(buf + m_ * 40 + m) = v;
            }
            #pragma unroll
            for (int u = 0; u < 2; u++) {
                int idx2 = u * 64 + lane;
                int chr = idx2 >> 2, q8 = idx2 & 3;
                s16x8 vv = *(const s16x8*)(buf + chr * 40 + q8 * 8);
                int oct = rowsub * 4 + q8;
                size_t e = (((((size_t)(b * 2 + chgv) * 64 + kt) * 8 + oct) * 4
                              + chslv) * 32 + chr) * 8;
                *(s16x8*)(v_frag + e) = vv;
            }
            __syncthreads();   // tbuf reuse across tiles within this wave group
        }
    }
}

// ---------- flash attention v8: balanced waves, TK=128, 1 barrier/iter -------
// grid (64 qt, 2 chg, 4 b) = 512 blocks, 512 thr = 8 waves.
// Wave (qsub=w&1, j=w>>1): S for 32q x keys[j*32..+31] of the 128-key tile
// (no intra-block S dup), then PV for 32q x ch[j*32..+31] over all 128 keys.
// P_s parity double-buffered -> one __syncthreads per 128-key iteration.
__global__ __launch_bounds__(512, 4) void attn_kernel(
    const _Float16* __restrict__ qf16, const _Float16* __restrict__ kf16,
    const unsigned short* __restrict__ v_frag,
    const float* __restrict__ x, const float* __restrict__ gamma_p,
    float* __restrict__ out)
{
    __shared__ __align__(16) unsigned short P_s[2][2][4096]; // [par][qsub][oct16][q32][8]
    __shared__ float l_s[2][4][32];                          // [qsub][j][q]

    const int tid  = threadIdx.x;
    const int lane = tid & 63;
    const int wave = tid >> 6;
    const int qsub = wave & 1;
    const int j    = wave >> 1;       // key-slice for S, ch-slice for PV
    const int m_   = lane & 31;
    const int k8   = lane >> 5;
    const int qt   = blockIdx.x;
    const int chg  = blockIdx.y;
    const int b    = blockIdx.z;
    const size_t bn = (size_t)b * N_;
    const int ch0  = chg * 128;
    const int octw = j * 4 + (m_ >> 3);   // P-write octet (0..15)
    const int osw  = octw & 3;
    const int kofs = m_ & 7;

    const unsigned short* vb = v_frag + (size_t)(b * 2 + chg) * 524288
                             + (size_t)k8 * 1024 + j * 256 + m_ * 8;

    const int qrow = qt * 64 + qsub * 32 + m_;
    const f16x8 Aq0 = *(const f16x8*)(qf16 + (bn + qrow) * 32 + k8 * 8);
    const f16x8 Aq1 = *(const f16x8*)(qf16 + (bn + qrow) * 32 + 16 + k8 * 8);

    // K fragment for iter 0 (keys j*32 + m_ of tile 0)
    const _Float16* kp0 = kf16 + (bn + j * 32 + m_) * 32;
    f16x8 Kc0 = *(const f16x8*)(kp0 + k8 * 8);
    f16x8 Kc1 = *(const f16x8*)(kp0 + 16 + k8 * 8);

    f32x16 acc;
    float l_acc[16];
    #pragma unroll
    for (int i = 0; i < 16; i++) { acc[i] = 0.f; l_acc[i] = 0.f; }

    for (int it = 0; it < 32; it++) {
        const int par = it & 1;
        // Bv for this iter: 2 64-key tiles x 4 frags (oct = t64*8 + ks*2 + k8)
        bf16x8 Bv[8];
        #pragma unroll
        for (int t64 = 0; t64 < 2; t64++)
            #pragma unroll
            for (int ks = 0; ks < 4; ks++)
                Bv[t64 * 4 + ks] = *(const bf16x8*)(vb
                    + (size_t)(it * 2 + t64) * 8192 + ks * 2048);
        // K prefetch for next iter
        const int itn = (it < 31) ? it + 1 : 31;
        const _Float16* kpn = kf16 + (bn + itn * 128 + j * 32 + m_) * 32;
        f16x8 Kn0 = *(const f16x8*)(kpn + k8 * 8);
        f16x8 Kn1 = *(const f16x8*)(kpn + 16 + k8 * 8);

        // S = Q K^T for this wave's 32-key slice
        f32x16 s;
        #pragma unroll
        for (int i = 0; i < 16; i++) s[i] = 0.f;
        s = __builtin_amdgcn_mfma_f32_32x32x16_f16(Aq0, Kc0, s, 0, 0, 0);
        s = __builtin_amdgcn_mfma_f32_32x32x16_f16(Aq1, Kc1, s, 0, 0, 0);

        // fixed-offset exp2 numerator; P -> LDS (b16, conflict-free pattern)
        unsigned short* Pb = P_s[par][qsub];
        #pragma unroll
        for (int r = 0; r < 16; r++) {
            float p = __builtin_amdgcn_exp2f(fmaf(s[r], LOG2E, -SOFT_OFF));
            l_acc[r] += p;
            int q = (r & 3) + 8 * (r >> 2) + 4 * k8;
            Pb[(octw * 32 + (q ^ osw)) * 8 + kofs] = f2bf_rh(p);
        }
        __syncthreads();   // P(par) visible; P(par^1) readers (prev iter) done

        // PV: O += P V over 16 key-octet steps (8 MFMAs, k8-split)
        const unsigned short* Pr = P_s[par][qsub];
        #pragma unroll
        for (int t64 = 0; t64 < 2; t64++)
            #pragma unroll
            for (int ks = 0; ks < 4; ks++) {
                int oct = t64 * 8 + ks * 2 + k8;
                bf16x8 Ap = *(const bf16x8*)(Pr + (oct * 32 + (m_ ^ (oct & 3))) * 8);
                acc = __builtin_amdgcn_mfma_f32_32x32x16_bf16(Ap, Bv[t64 * 4 + ks],
                                                              acc, 0, 0, 0);
            }
        Kc0 = Kn0; Kc1 = Kn1;
    }

    // l: per-wave reduce over its 32 key-cols, publish, sum 4 slices
    #pragma unroll
    for (int off = 1; off < 32; off <<= 1)
        #pragma unroll
        for (int r = 0; r < 16; r++)
            l_acc[r] += __shfl_xor(l_acc[r], off, 64);
    if (m_ == 0) {
        #pragma unroll
        for (int r = 0; r < 16; r++) {
            int q = (r & 3) + 8 * (r >> 2) + 4 * k8;
            l_s[qsub][j][q] = l_acc[r];
        }
    }
    __syncthreads();

    const float gamma = *gamma_p;
    #pragma unroll
    for (int r = 0; r < 16; r++) {
        int q = (r & 3) + 8 * (r >> 2) + 4 * k8;
        float l = l_s[qsub][0][q] + l_s[qsub][1][q]
                + l_s[qsub][2][q] + l_s[qsub][3][q];
        size_t idx = (bn + qt * 64 + qsub * 32 + q) * 256 + ch0 + j * 32 + m_;
        out[idx] = gamma * (acc[r] / l) + x[idx];
    }
}

extern "C" void kernel_launch(void* const* d_in, const int* in_sizes, int n_in,
                              void* d_out, int out_size, void* d_ws, size_t ws_size,
                              hipStream_t stream) {
    const float* x   = (const float*)d_in[0];
    const float* Wf  = (const float*)d_in[1];
    const float* bfp = (const float*)d_in[2];
    const float* Wg  = (const float*)d_in[3];
    const float* bgp = (const float*)d_in[4];
    const float* Wh  = (const float*)d_in[5];
    const float* bhp = (const float*)d_in[6];
    const float* gam = (const float*)d_in[7];
    float* out = (float*)d_out;

    unsigned char* ws = (unsigned char*)d_ws;
    const size_t MB = 1 << 20;
    _Float16* WT    = (_Float16*)(ws);              // [320][256] f16, 160 KB
    _Float16* qf16  = (_Float16*)(ws + 1 * MB);     // [B*N][32] f16 (queries g)
    _Float16* kf16  = (_Float16*)(ws + 2 * MB);     // [B*N][32] f16 (keys f)
    unsigned short* v_frag = (unsigned short*)(ws + 3 * MB);  // 8.4 MB B-frag layout

    wprep<<<dim3(10, 4), dim3(256), 0, stream>>>(Wf, Wg, Wh, WT);
    proj_kernel<<<dim3(256, 2), dim3(256), 0, stream>>>(
        x, bfp, bgp, bhp, WT, qf16, kf16, v_frag);
    attn_kernel<<<dim3(64, 2, 4), dim3(512), 0, stream>>>(
        qf16, kf16, v_frag, x, gam, out);
}

// Round 9
// 150.944 us; speedup vs baseline: 1.3835x; 1.1434x over previous
//
#include <hip/hip_runtime.h>
#include <stdint.h>

#define B_ 4
#define N_ 4096
#define C_ 256
#define LOG2E 1.44269504088896340736f
#define SOFT_OFF 88.0f

typedef float f32x4 __attribute__((ext_vector_type(4)));
typedef float f32x16 __attribute__((ext_vector_type(16)));
typedef short s16x8 __attribute__((ext_vector_type(8)));
typedef __bf16 bf16x8 __attribute__((ext_vector_type(8)));
typedef _Float16 f16x8 __attribute__((ext_vector_type(8)));

static __device__ __forceinline__ unsigned short f2bf(float f) {
    union { float f; uint32_t u; } v; v.f = f;
    return (unsigned short)((v.u + 0x7FFFu + ((v.u >> 16) & 1u)) >> 16);
}
static __device__ __forceinline__ unsigned short f2bf_rh(float f) {
    union { float f; uint32_t u; } v; v.f = f;
    return (unsigned short)((v.u + 0x8000u) >> 16);
}

// ---------- wprep: coalesced LDS transpose, W -> WT f16 [320][256] ----------
__global__ __launch_bounds__(256) void wprep(
    const float* __restrict__ Wf, const float* __restrict__ Wg,
    const float* __restrict__ Wh, _Float16* __restrict__ WT)
{
    __shared__ float tile[64][33];
    const int t = blockIdx.x, kc = blockIdx.y, tid = threadIdx.x;
    const float* src; int stride;
    if (t == 0)      { src = Wf;                stride = 32;  }
    else if (t == 1) { src = Wg;                stride = 32;  }
    else             { src = Wh + (t - 2) * 32; stride = 256; }

    const int c = tid & 31, a = tid >> 5;
    #pragma unroll
    for (int p = 0; p < 8; p++) {
        int kk = p * 8 + a;
        tile[kk][c] = src[(size_t)(kc * 64 + kk) * stride + c];
    }
    __syncthreads();
    const int kk = tid & 63, aa = tid >> 6;
    #pragma unroll
    for (int p = 0; p < 8; p++) {
        int cc = p * 4 + aa;
        WT[(size_t)(t * 32 + cc) * 256 + kc * 64 + kk] = (_Float16)tile[kk][cc];
    }
}

// ---------- proj v7: 3 tiles/wave, x read 2x, batched reg-prefetch -----------
__global__ __launch_bounds__(256, 2) void proj_kernel(
    const float* __restrict__ x,
    const float* __restrict__ bfp, const float* __restrict__ bgp,
    const float* __restrict__ bhp,
    const _Float16* __restrict__ WT,
    _Float16* __restrict__ qf16, _Float16* __restrict__ kf16,
    unsigned short* __restrict__ v_frag)
{
    __shared__ __align__(16) _Float16 xs[64 * 256];            // 32 KB, swizzled
    __shared__ __align__(16) unsigned short tbuf[4][32 * 40];  // 10 KB

    const int tid  = threadIdx.x;
    const int lane = tid & 63;
    const int wave = tid >> 6;
    const int m_   = lane & 31;
    const int k8   = lane >> 5;
    const int row0 = blockIdx.x * 64;
    const int half = blockIdx.y;
    const int b    = row0 >> 12;
    const int n0   = row0 & 4095;
    const int kt   = n0 >> 6;

    #pragma unroll
    for (int i = 0; i < 8; i++) {
        int r  = 8 * i + (tid >> 5);
        int c5 = tid & 31;
        const f32x4* src = (const f32x4*)(x + (size_t)(row0 + r) * 256 + c5 * 8);
        f32x4 a = src[0], c4 = src[1];
        f16x8 h = { (_Float16)a.x, (_Float16)a.y, (_Float16)a.z, (_Float16)a.w,
                    (_Float16)c4.x, (_Float16)c4.y, (_Float16)c4.z, (_Float16)c4.w };
        int chunk = (((r >> 5) * 32 + c5)) * 32 + ((r & 31) ^ (c5 & 7));
        *(f16x8*)(xs + chunk * 8) = h;
    }
    __syncthreads();

    const int rowsub = wave & 1;
    const int tg     = wave >> 1;
    const int ntile  = (half == 0) ? 3 : 2;
    const int t_base = (half == 0) ? tg * 3 : 6 + tg * 2;
    const _Float16* wb[3];
    #pragma unroll
    for (int t = 0; t < 3; t++)
        wb[t] = WT + (size_t)((t_base + (t < ntile ? t : 0)) * 32 + m_) * 256 + k8 * 8;

    f32x16 acc[3];
    #pragma unroll
    for (int t = 0; t < 3; t++)
        #pragma unroll
        for (int i = 0; i < 16; i++) acc[t][i] = 0.f;

    f16x8 Bb[2][4][3];
    #pragma unroll
    for (int j = 0; j < 4; j++)
        #pragma unroll
        for (int t = 0; t < 3; t++) {
            if (t >= ntile) break;
            Bb[0][j][t] = *(const f16x8*)(wb[t] + j * 16);
        }
    #pragma unroll
    for (int g4 = 0; g4 < 4; g4++) {
        const int cur = g4 & 1, nxt = cur ^ 1;
        if (g4 < 3)
            #pragma unroll
            for (int j = 0; j < 4; j++)
                #pragma unroll
                for (int t = 0; t < 3; t++) {
                    if (t >= ntile) break;
                    Bb[nxt][j][t] = *(const f16x8*)(wb[t] + (g4 * 4 + 4 + j) * 16);
                }
        #pragma unroll
        for (int j = 0; j < 4; j++) {
            int ks = g4 * 4 + j;
            f16x8 A = *(const f16x8*)(xs + ((rowsub * 32 + ks * 2 + k8) * 32
                                            + (m_ ^ ((ks * 2 + k8) & 7))) * 8);
            #pragma unroll
            for (int t = 0; t < 3; t++) {
                if (t >= ntile) break;
                acc[t] = __builtin_amdgcn_mfma_f32_32x32x16_f16(A, Bb[cur][j][t],
                                                                acc[t], 0, 0, 0);
            }
        }
    }

    #pragma unroll
    for (int t = 0; t < 3; t++) {
        if (t >= ntile) break;
        const int tile = t_base + t;
        if (tile < 2) {            // f -> kf16, g -> qf16
            float bias = (tile == 0) ? bfp[m_] : bgp[m_];
            _Float16* dst = (tile == 0) ? kf16 : qf16;
            #pragma unroll
            for (int r = 0; r < 16; r++) {
                int m = (r & 3) + 8 * (r >> 2) + 4 * k8;
                int row = row0 + rowsub * 32 + m;
                dst[(size_t)row * 32 + m_] = (_Float16)(acc[t][r] + bias);
            }
        } else {                   // h -> v_frag[b][chg][kt][oct][chsl][ch32][key8]
            const int ht   = tile - 2;
            const int chgv = ht >> 2, chslv = ht & 3;
            float bias = bhp[ht * 32 + m_];
            unsigned short* buf = tbuf[wave];
            // per-wave buffer; DS ops from one wave execute in order -> no barrier
            #pragma unroll
            for (int u = 0; u < 8; u++) {
                int r = 2 * u;
                int m = (r & 3) + 8 * (r >> 2) + 4 * k8;
                uint32_t v = (uint32_t)f2bf(acc[t][r] + bias)
                           | ((uint32_t)f2bf(acc[t][r + 1] + bias) << 16);
                *(uint32_t*)(buf + m_ * 40 + m) = v;
            }
            #pragma unroll
            for (int u = 0; u < 2; u++) {
                int idx2 = u * 64 + lane;
                int chr = idx2 >> 2, q8 = idx2 & 3;
                s16x8 vv = *(const s16x8*)(buf + chr * 40 + q8 * 8);
                int oct = rowsub * 4 + q8;
                size_t e = (((((size_t)(b * 2 + chgv) * 64 + kt) * 8 + oct) * 4
                              + chslv) * 32 + chr) * 8;
                *(s16x8*)(v_frag + e) = vv;
            }
        }
    }
}

// ---------- flash attention v9: 1024 thr, full 256 ch, no S dup --------------
// grid (64 qt, 4 b) = 256 blocks, 16 waves. Wave (qsub=w&1, j=w>>1):
// S (waves 0-7 only): keys [kslice j]*32 of the 128-key tile -> P_s[par][qsub].
// PV (all 16): ch-slice j (32 ch) over all 128 keys, Bv direct from v_frag.
// P parity-dbuf -> one __syncthreads per iter; Bv batch1 loaded post-barrier.
__global__ __launch_bounds__(1024, 4) void attn_kernel(
    const _Float16* __restrict__ qf16, const _Float16* __restrict__ kf16,
    const unsigned short* __restrict__ v_frag,
    const float* __restrict__ x, const float* __restrict__ gamma_p,
    float* __restrict__ out)
{
    __shared__ __align__(16) unsigned short P_s[2][2][4096]; // [par][qsub][16oct][32q][8]
    __shared__ float l_s[2][4][32];                          // [qsub][kslice][q]

    const int tid  = threadIdx.x;
    const int lane = tid & 63;
    const int wave = tid >> 6;        // 0..15
    const int qsub = wave & 1;
    const int j    = wave >> 1;       // ch-slice 0..7; key-slice for S (j<4)
    const int m_   = lane & 31;
    const int k8   = lane >> 5;
    const int qt   = blockIdx.x;
    const int b    = blockIdx.y;
    const size_t bn = (size_t)b * N_;
    const bool is_s = (wave < 8);
    const int ksl  = j;               // S key-slice (valid when is_s)
    const int octw = ksl * 4 + (m_ >> 3);
    const int osw  = octw & 3;
    const int kofs = m_ & 7;

    // v_frag base for ch-slice j (chg = j>>2, chsl = j&3)
    const unsigned short* vb = v_frag + (size_t)(b * 2 + (j >> 2)) * 524288
                             + (j & 3) * 256 + m_ * 8;
    // frag(it, oct): vb + it*16384 + (oct>>3)*8192 + (oct&7)*1024, oct=0..15

    const int qrow = qt * 64 + qsub * 32 + m_;
    const f16x8 Aq0 = *(const f16x8*)(qf16 + (bn + qrow) * 32 + k8 * 8);
    const f16x8 Aq1 = *(const f16x8*)(qf16 + (bn + qrow) * 32 + 16 + k8 * 8);

    f16x8 Kc0 = {}, Kc1 = {};
    if (is_s) {
        const _Float16* kp = kf16 + (bn + ksl * 32 + m_) * 32;
        Kc0 = *(const f16x8*)(kp + k8 * 8);
        Kc1 = *(const f16x8*)(kp + 16 + k8 * 8);
    }
    // prologue: Bv batch0 (ks 0..3 -> oct 0..7) of iter 0
    bf16x8 Bv0[4], Bv1[4];
    #pragma unroll
    for (int ks = 0; ks < 4; ks++)
        Bv0[ks] = *(const bf16x8*)(vb + (ks * 2 + k8) * 1024);

    f32x16 acc;
    float l_acc[16];
    #pragma unroll
    for (int i = 0; i < 16; i++) { acc[i] = 0.f; l_acc[i] = 0.f; }

    for (int it = 0; it < 32; it++) {
        const int par = it & 1;
        const int itn = (it < 31) ? it + 1 : 31;
        // K prefetch for next iter (S-waves)
        f16x8 Kn0 = {}, Kn1 = {};
        if (is_s) {
            const _Float16* kp = kf16 + (bn + itn * 128 + ksl * 32 + m_) * 32;
            Kn0 = *(const f16x8*)(kp + k8 * 8);
            Kn1 = *(const f16x8*)(kp + 16 + k8 * 8);
            // S = Q K^T for this wave's 32-key slice
            f32x16 s;
            #pragma unroll
            for (int i = 0; i < 16; i++) s[i] = 0.f;
            s = __builtin_amdgcn_mfma_f32_32x32x16_f16(Aq0, Kc0, s, 0, 0, 0);
            s = __builtin_amdgcn_mfma_f32_32x32x16_f16(Aq1, Kc1, s, 0, 0, 0);
            // fixed-offset exp2 numerator; P -> LDS (b16, conflict-free)
            unsigned short* Pb = P_s[par][qsub];
            #pragma unroll
            for (int r = 0; r < 16; r++) {
                float p = __builtin_amdgcn_exp2f(fmaf(s[r], LOG2E, -SOFT_OFF));
                l_acc[r] += p;
                int q = (r & 3) + 8 * (r >> 2) + 4 * k8;
                Pb[(octw * 32 + (q ^ osw)) * 8 + kofs] = f2bf_rh(p);
            }
        }
        __syncthreads();   // P(par) visible; P(par) of it-2 readers long done

        const unsigned short* Pr = P_s[par][qsub];
        // load batch1 (oct 8..15) post-barrier; covered by batch0 PV + TLP
        #pragma unroll
        for (int ks = 0; ks < 4; ks++)
            Bv1[ks] = *(const bf16x8*)(vb + (size_t)it * 16384 + 8192
                                       + (ks * 2 + k8) * 1024);
        #pragma unroll
        for (int ks = 0; ks < 4; ks++) {
            int oct = ks * 2 + k8;
            bf16x8 Ap = *(const bf16x8*)(Pr + (oct * 32 + (m_ ^ (oct & 3))) * 8);
            acc = __builtin_amdgcn_mfma_f32_32x32x16_bf16(Ap, Bv0[ks], acc, 0, 0, 0);
        }
        #pragma unroll
        for (int ks = 0; ks < 4; ks++) {
            int oct = 8 + ks * 2 + k8;
            bf16x8 Ap = *(const bf16x8*)(Pr + (oct * 32 + (m_ ^ (oct & 3))) * 8);
            acc = __builtin_amdgcn_mfma_f32_32x32x16_bf16(Ap, Bv1[ks], acc, 0, 0, 0);
        }
        // prefetch batch0 of next iter (in flight across next barrier's S phase)
        #pragma unroll
        for (int ks = 0; ks < 4; ks++)
            Bv0[ks] = *(const bf16x8*)(vb + (size_t)itn * 16384
                                       + (ks * 2 + k8) * 1024);
        if (is_s) { Kc0 = Kn0; Kc1 = Kn1; }
    }

    // l: S-waves reduce over their 32 key-cols, publish, all combine 4 slices
    if (is_s) {
        #pragma unroll
        for (int off = 1; off < 32; off <<= 1)
            #pragma unroll
            for (int r = 0; r < 16; r++)
                l_acc[r] += __shfl_xor(l_acc[r], off, 64);
        if (m_ == 0) {
            #pragma unroll
            for (int r = 0; r < 16; r++) {
                int q = (r & 3) + 8 * (r >> 2) + 4 * k8;
                l_s[qsub][ksl][q] = l_acc[r];
            }
        }
    }
    __syncthreads();

    const float gamma = *gamma_p;
    #pragma unroll
    for (int r = 0; r < 16; r++) {
        int q = (r & 3) + 8 * (r >> 2) + 4 * k8;
        float l = l_s[qsub][0][q] + l_s[qsub][1][q]
                + l_s[qsub][2][q] + l_s[qsub][3][q];
        size_t idx = (bn + qt * 64 + qsub * 32 + q) * 256 + j * 32 + m_;
        out[idx] = gamma * (acc[r] / l) + x[idx];
    }
}

extern "C" void kernel_launch(void* const* d_in, const int* in_sizes, int n_in,
                              void* d_out, int out_size, void* d_ws, size_t ws_size,
                              hipStream_t stream) {
    const float* x   = (const float*)d_in[0];
    const float* Wf  = (const float*)d_in[1];
    const float* bfp = (const float*)d_in[2];
    const float* Wg  = (const float*)d_in[3];
    const float* bgp = (const float*)d_in[4];
    const float* Wh  = (const float*)d_in[5];
    const float* bhp = (const float*)d_in[6];
    const float* gam = (const float*)d_in[7];
    float* out = (float*)d_out;

    unsigned char* ws = (unsigned char*)d_ws;
    const size_t MB = 1 << 20;
    _Float16* WT    = (_Float16*)(ws);              // [320][256] f16, 160 KB
    _Float16* qf16  = (_Float16*)(ws + 1 * MB);     // [B*N][32] f16 (queries g)
    _Float16* kf16  = (_Float16*)(ws + 2 * MB);     // [B*N][32] f16 (keys f)
    unsigned short* v_frag = (unsigned short*)(ws + 3 * MB);  // 8.4 MB B-frag layout

    wprep<<<dim3(10, 4), dim3(256), 0, stream>>>(Wf, Wg, Wh, WT);
    proj_kernel<<<dim3(256, 2), dim3(256), 0, stream>>>(
        x, bfp, bgp, bhp, WT, qf16, kf16, v_frag);
    attn_kernel<<<dim3(64, 4), dim3(1024), 0, stream>>>(
        qf16, kf16, v_frag, x, gam, out);
}